// Round 6
// baseline (314.276 us; speedup 1.0000x reference)
//
#include <hip/hip_runtime.h>

// SimpleGraphSAGE on MI355X — round 6.
// dst = repeat(arange(N),16) -> node i's edges are src[16i..16i+16), deg==16.
//
// History: R1 85us/layer (LDS-bound matmul), R3 83 (SGPR-W matmul, fp32
// gather), R4 72 (bf16 gather, FETCH 188->90MB), R5 73.5 (4-rows-per-load:
// 4x fewer gather insts, FLAT -> not instruction-bound).
// R5 analysis: gather is MLP-bound (Little's law: ~22 rows in flight/CU at
// ~500cyc latency explains 23 cyc/row). The fused kernel caps occupancy at
// 4 blocks/CU (37KB LDS) and half the waves sit in the vmem-free matmul
// phase. R6: SPLIT — a zero-LDS, 24-waves/CU gather kernel with >=16 rows
// in flight per wave, plus a pure-streaming dense-matmul kernel.

#define NN   100000
#define DEG  16
#define F    64
#define KDIM 128
#define NPB  64       // nodes per dense block
#define STR  65       // LDS row stride (2-way bank alias = free)
#define JPW  16       // output columns per wave
#define EDG  (NN * DEG)

__device__ __forceinline__ ushort f2bf(float f) {        // RNE
    unsigned u = __float_as_uint(f);
    return (ushort)((u + 0x7fffu + ((u >> 16) & 1u)) >> 16);
}
__device__ __forceinline__ float bf2f(ushort u) {
    return __uint_as_float(((unsigned)u) << 16);
}

__global__ __launch_bounds__(256)
void cvt_f32_bf16(const float* __restrict__ in, ushort* __restrict__ out, int n4)
{
    int i = blockIdx.x * 256 + threadIdx.x;
    if (i < n4) {
        float4 v = ((const float4*)in)[i];
        ushort4 o;
        o.x = f2bf(v.x); o.y = f2bf(v.y); o.z = f2bf(v.z); o.w = f2bf(v.w);
        ((ushort4*)out)[i] = o;
    }
}

// ---------------- max-MLP gather/mean kernel ----------------
// One 8-lane group per node: sub-lane s holds features 8s..8s+8 (16B bf16).
// 4 independent accumulator sets -> >=16 row loads in flight per wave.
// No LDS, ~70 VGPR, 6 blocks/CU -> ~24 resident waves/CU.
__global__ __launch_bounds__(256, 6)
void gather_mean_bf(const ushort* __restrict__ gat,   // [NN,F] bf16
                    const int*    __restrict__ src,   // [EDG]
                    ushort*       __restrict__ hn)    // [NN,F] bf16 mean
{
    const int tid  = threadIdx.x;
    const int lane = tid & 63;
    const int wave = tid >> 6;
    const int sub  = lane & 7;                        // 16B feature chunk
    const int grp  = lane >> 3;                       // node within wave
    const int node = blockIdx.x * 32 + wave * 8 + grp;   // 3125*32 == NN

    const int* sp = src + node * DEG;

    float a0[8], a1[8], a2[8], a3[8];
    #pragma unroll
    for (int f = 0; f < 8; ++f) { a0[f] = a1[f] = a2[f] = a3[f] = 0.f; }

    #pragma unroll
    for (int e4 = 0; e4 < DEG / 4; ++e4) {
        const int4 ii = *(const int4*)(sp + 4 * e4);  // same within group
        const uint4 r0 = *(const uint4*)(gat + (size_t)ii.x * F + sub * 8);
        const uint4 r1 = *(const uint4*)(gat + (size_t)ii.y * F + sub * 8);
        const uint4 r2 = *(const uint4*)(gat + (size_t)ii.z * F + sub * 8);
        const uint4 r3 = *(const uint4*)(gat + (size_t)ii.w * F + sub * 8);
        #pragma unroll
        for (int t = 0; t < 4; ++t) {
            const unsigned w0 = (&r0.x)[t], w1 = (&r1.x)[t];
            const unsigned w2 = (&r2.x)[t], w3 = (&r3.x)[t];
            a0[2*t]   += __uint_as_float(w0 << 16);
            a0[2*t+1] += __uint_as_float(w0 & 0xffff0000u);
            a1[2*t]   += __uint_as_float(w1 << 16);
            a1[2*t+1] += __uint_as_float(w1 & 0xffff0000u);
            a2[2*t]   += __uint_as_float(w2 << 16);
            a2[2*t+1] += __uint_as_float(w2 & 0xffff0000u);
            a3[2*t]   += __uint_as_float(w3 << 16);
            a3[2*t+1] += __uint_as_float(w3 & 0xffff0000u);
        }
    }

    uint4 p;
    #pragma unroll
    for (int t = 0; t < 4; ++t) {
        const float lo = ((a0[2*t]   + a1[2*t])   + (a2[2*t]   + a3[2*t]))
                         * (1.0f / DEG);
        const float hi = ((a0[2*t+1] + a1[2*t+1]) + (a2[2*t+1] + a3[2*t+1]))
                         * (1.0f / DEG);
        (&p.x)[t] = (unsigned)f2bf(lo) | ((unsigned)f2bf(hi) << 16);
    }
    *(uint4*)(hn + (size_t)node * F + sub * 8) = p;   // coalesced 128B/node
}

// ---------------- streaming dense layer ----------------
// out = act(concat(self_f32, hn_bf16) @ W + b). All reads coalesced.
template<bool RELU, bool EMIT_BF16>
__global__ __launch_bounds__(256, 4)
void sage_dense(const float*  __restrict__ self_f32,  // [NN,F]
                const ushort* __restrict__ hn_bf16,   // [NN,F] bf16 means
                const float*  __restrict__ W,         // [KDIM,F]
                const float*  __restrict__ bias,      // [F]
                float*        __restrict__ out_f32,   // [NN,F]
                ushort*       __restrict__ out_bf16)  // [NN,F] or null
{
    __shared__ float buf[KDIM][STR];   // 33.3 KB, k-major

    const int tid   = threadIdx.x;
    const int lane  = tid & 63;
    const int wave  = __builtin_amdgcn_readfirstlane(tid >> 6);
    const int node0 = blockIdx.x * NPB;

    // Stage: lane = feature; wave stages its 16 nodes. Both streams coalesced.
    #pragma unroll 4
    for (int m = 0; m < NPB / 4; ++m) {
        const int n    = wave * (NPB / 4) + m;
        const int node = node0 + n;
        float v = 0.f, s = 0.f;
        if (node < NN) {
            v = self_f32[node * F + lane];                // 256B row
            s = bf2f(hn_bf16[node * F + lane]);           // 128B row
        }
        buf[lane][n]     = v;
        buf[F + lane][n] = s;
    }
    __syncthreads();

    // Matmul: lane = node, wave owns j in [16w,16w+16). W row wave-uniform
    // -> s_load; buf[k][lane] ds_read_b32 2-way alias = free.
    const int j0 = wave * JPW;
    float acc[JPW];
    #pragma unroll
    for (int j = 0; j < JPW; ++j) acc[j] = bias[j0 + j];

    #pragma unroll 4
    for (int k = 0; k < KDIM; ++k) {
        const float v = buf[k][lane];
        const float* Wr = W + k * F + j0;
        #pragma unroll
        for (int j = 0; j < JPW; ++j)
            acc[j] = fmaf(v, Wr[j], acc[j]);
    }

    const int node = node0 + lane;
    if (node < NN) {
        if (RELU) {
            #pragma unroll
            for (int j = 0; j < JPW; ++j) acc[j] = fmaxf(acc[j], 0.f);
        }
        float4* op = (float4*)(out_f32 + node * F + j0);
        #pragma unroll
        for (int t = 0; t < 4; ++t)
            op[t] = make_float4(acc[4 * t], acc[4 * t + 1],
                                acc[4 * t + 2], acc[4 * t + 3]);
        if (EMIT_BF16) {
            uint4 p0, p1;
            #pragma unroll
            for (int t = 0; t < 8; ++t)
                (t < 4 ? (&p0.x)[t] : (&p1.x)[t - 4]) =
                    (unsigned)f2bf(acc[2 * t]) |
                    ((unsigned)f2bf(acc[2 * t + 1]) << 16);
            uint4* ob = (uint4*)(out_bf16 + node * F + j0);  // 32B aligned
            ob[0] = p0; ob[1] = p1;
        }
    }
}

// ---------------- fallback (round-3, all-fp32, fused) ----------------
template<bool RELU>
__global__ __launch_bounds__(256, 4)
void sage_layer_f32(const float* __restrict__ feat,
                    const float* __restrict__ W,
                    const float* __restrict__ bias,
                    const int*   __restrict__ src,
                    float*       __restrict__ out)
{
    __shared__ float buf[KDIM][STR];
    const int tid   = threadIdx.x;
    const int lane  = tid & 63;
    const int wave  = __builtin_amdgcn_readfirstlane(tid >> 6);
    const int node0 = blockIdx.x * NPB;

    #pragma unroll 2
    for (int m = 0; m < NPB / 4; ++m) {
        const int n    = wave * (NPB / 4) + m;
        const int node = node0 + n;
        if (node < NN) {
            buf[lane][n] = feat[node * F + lane];
            const int* sp = src + node * DEG;
            float s = 0.f;
            #pragma unroll
            for (int e = 0; e < DEG; ++e) s += feat[sp[e] * F + lane];
            buf[F + lane][n] = s * (1.0f / DEG);
        }
    }
    __syncthreads();

    const int j0 = wave * JPW;
    float acc[JPW];
    #pragma unroll
    for (int j = 0; j < JPW; ++j) acc[j] = bias[j0 + j];
    #pragma unroll 4
    for (int k = 0; k < KDIM; ++k) {
        const float v = buf[k][lane];
        const float* Wr = W + k * F + j0;
        #pragma unroll
        for (int j = 0; j < JPW; ++j) acc[j] = fmaf(v, Wr[j], acc[j]);
    }
    const int node = node0 + lane;
    if (node < NN) {
        float4* op = (float4*)(out + node * F + j0);
        #pragma unroll
        for (int t = 0; t < 4; ++t) {
            float4 r = make_float4(acc[4 * t], acc[4 * t + 1],
                                   acc[4 * t + 2], acc[4 * t + 3]);
            if (RELU) {
                r.x = fmaxf(r.x, 0.f); r.y = fmaxf(r.y, 0.f);
                r.z = fmaxf(r.z, 0.f); r.w = fmaxf(r.w, 0.f);
            }
            op[t] = r;
        }
    }
}

extern "C" void kernel_launch(void* const* d_in, const int* in_sizes, int n_in,
                              void* d_out, int out_size, void* d_ws, size_t ws_size,
                              hipStream_t stream) {
    const float* x   = (const float*)d_in[0];
    const float* W1  = (const float*)d_in[1];
    const float* b1  = (const float*)d_in[2];
    const float* W2  = (const float*)d_in[3];
    const float* b2  = (const float*)d_in[4];
    const int*   src = (const int*)d_in[5];

    float* out = (float*)d_out;
    const int dblocks = (NN + NPB - 1) / NPB;   // 1563
    const int gblocks = NN / 32;                // 3125 (exact)

    const size_t hF32 = (size_t)NN * F * sizeof(float);   // 25.6 MB
    const size_t hBF  = (size_t)NN * F * sizeof(ushort);  // 12.8 MB

    if (ws_size >= hF32 + 2 * hBF) {
        // Buffer plan (51.2 MB total, same as R4):
        //   C = h_f32 (25.6MB), A = x_bf16 then h_bf16 (12.8MB), B = hn (12.8MB)
        float*  C = (float*)d_ws;
        ushort* A = (ushort*)((char*)d_ws + hF32);
        ushort* B = (ushort*)((char*)d_ws + hF32 + hBF);

        const int n4 = NN * F / 4;
        cvt_f32_bf16<<<(n4 + 255) / 256, 256, 0, stream>>>(x, A, n4);
        gather_mean_bf<<<gblocks, 256, 0, stream>>>(A, src, B);       // hn1
        sage_dense<true,  true ><<<dblocks, 256, 0, stream>>>(
            x, B, W1, b1, C, A);                                      // h, h_bf16
        gather_mean_bf<<<gblocks, 256, 0, stream>>>(A, src, B);       // hn2
        sage_dense<false, false><<<dblocks, 256, 0, stream>>>(
            C, B, W2, b2, out, nullptr);
    } else {
        float* h = (float*)d_ws;
        sage_layer_f32<true ><<<dblocks, 256, 0, stream>>>(x, W1, b1, src, h);
        sage_layer_f32<false><<<dblocks, 256, 0, stream>>>(h, W2, b2, src, out);
    }
}

// Round 7
// 287.491 us; speedup vs baseline: 1.0932x; 1.0932x over previous
//
#include <hip/hip_runtime.h>

// SimpleGraphSAGE on MI355X — round 7.
// dst = repeat(arange(N),16) -> node i's edges are src[16i..16i+16), deg==16.
//
// History: R1 85us/layer, R3 83, R4 72 (bf16 gather), R5 73.5 (4-rows/load,
// flat), R6 split gather 70us standalone (51% occ, flat).
// Invariant found: ~20 cyc per random L1-miss line per CU across ALL designs
// -> per-CU outstanding-miss slots x avg latency is the currency.
// R7: reduce LATENCY. Sort each node's 16 srcs (Batcher-16 in registers);
// device processes edges in ascending-src order -> all CUs read a moving
// ~2.8MB window -> same-XCD L2 hits (~200cyc) instead of fabric (~500cyc).
// Gather grid sized to be fully co-resident (one cohort, windows coherent).

#define NN   100000
#define DEG  16
#define F    64
#define KDIM 128
#define NPB  64       // nodes per dense block
#define STR  65       // LDS row stride (2-way bank alias = free)
#define JPW  16       // output columns per wave
#define EDG  (NN * DEG)
#define GNPB 64       // nodes per gather block
#define GBLK ((NN + GNPB - 1) / GNPB)   // 1563 blocks ~= 6.1/CU, co-resident

__device__ __forceinline__ ushort f2bf(float f) {        // RNE
    unsigned u = __float_as_uint(f);
    return (ushort)((u + 0x7fffu + ((u >> 16) & 1u)) >> 16);
}
__device__ __forceinline__ float bf2f(ushort u) {
    return __uint_as_float(((unsigned)u) << 16);
}

__global__ __launch_bounds__(256)
void cvt_f32_bf16(const float* __restrict__ in, ushort* __restrict__ out, int n4)
{
    int i = blockIdx.x * 256 + threadIdx.x;
    if (i < n4) {
        float4 v = ((const float4*)in)[i];
        ushort4 o;
        o.x = f2bf(v.x); o.y = f2bf(v.y); o.z = f2bf(v.z); o.w = f2bf(v.w);
        ((ushort4*)out)[i] = o;
    }
}

// Batcher odd-even mergesort, 16 keys, fully unrolled -> stays in registers.
__device__ __forceinline__ void ce(unsigned& a, unsigned& b) {
    const unsigned lo = min(a, b), hi = max(a, b); a = lo; b = hi;
}
__device__ __forceinline__ void sort16(unsigned s[16]) {
    #pragma unroll
    for (int p = 1; p < 16; p <<= 1) {
        #pragma unroll
        for (int k = p; k >= 1; k >>= 1) {
            #pragma unroll
            for (int j = k & (p - 1); j + k < 16; j += 2 * k) {
                #pragma unroll
                for (int i = 0; i < k; ++i) {
                    if (i + j + k < 16)
                        if ((i + j) / (2 * p) == (i + j + k) / (2 * p))
                            ce(s[i + j], s[i + j + k]);
                }
            }
        }
    }
}

// ---------------- sorted-window gather/mean kernel ----------------
// 8-lane group handles 2 nodes; sub-lane s holds features 8s..8s+8 (16B).
// Both nodes' sorted src streams are walked in lockstep (4 rows in flight).
__global__ __launch_bounds__(256, 6)
void gather_mean_sorted(const ushort* __restrict__ gat,  // [NN,F] bf16
                        const int*    __restrict__ src,  // [EDG]
                        ushort*       __restrict__ hn)   // [NN,F] bf16 mean
{
    const int tid  = threadIdx.x;
    const int lane = tid & 63;
    const int wave = tid >> 6;
    const int sub  = lane & 7;
    const int grp  = lane >> 3;
    const int n0   = blockIdx.x * GNPB + wave * 16 + grp * 2;
    const int n1   = n0 + 1;
    const bool v0  = n0 < NN, v1 = n1 < NN;

    // Every lane of the group redundantly holds its two nodes' 16 srcs.
    unsigned s0[DEG], s1[DEG];
    {
        const int4* p0 = (const int4*)(src + (size_t)n0 * DEG);
        const int4* p1 = (const int4*)(src + (size_t)n1 * DEG);
        #pragma unroll
        for (int q = 0; q < 4; ++q) {
            const int4 a = v0 ? p0[q] : make_int4(0, 0, 0, 0);
            const int4 b = v1 ? p1[q] : make_int4(0, 0, 0, 0);
            s0[4*q+0] = a.x; s0[4*q+1] = a.y; s0[4*q+2] = a.z; s0[4*q+3] = a.w;
            s1[4*q+0] = b.x; s1[4*q+1] = b.y; s1[4*q+2] = b.z; s1[4*q+3] = b.w;
        }
    }
    sort16(s0);
    sort16(s1);

    float a0[8], a1[8];
    #pragma unroll
    for (int f = 0; f < 8; ++f) { a0[f] = 0.f; a1[f] = 0.f; }

    #pragma unroll
    for (int e = 0; e < DEG; e += 2) {
        const uint4 r00 = *(const uint4*)(gat + (size_t)s0[e]     * F + sub * 8);
        const uint4 r01 = *(const uint4*)(gat + (size_t)s0[e + 1] * F + sub * 8);
        const uint4 r10 = *(const uint4*)(gat + (size_t)s1[e]     * F + sub * 8);
        const uint4 r11 = *(const uint4*)(gat + (size_t)s1[e + 1] * F + sub * 8);
        #pragma unroll
        for (int t = 0; t < 4; ++t) {
            const unsigned w00 = (&r00.x)[t], w01 = (&r01.x)[t];
            const unsigned w10 = (&r10.x)[t], w11 = (&r11.x)[t];
            a0[2*t]   += __uint_as_float(w00 << 16);
            a0[2*t+1] += __uint_as_float(w00 & 0xffff0000u);
            a0[2*t]   += __uint_as_float(w01 << 16);
            a0[2*t+1] += __uint_as_float(w01 & 0xffff0000u);
            a1[2*t]   += __uint_as_float(w10 << 16);
            a1[2*t+1] += __uint_as_float(w10 & 0xffff0000u);
            a1[2*t]   += __uint_as_float(w11 << 16);
            a1[2*t+1] += __uint_as_float(w11 & 0xffff0000u);
        }
    }

    uint4 p0, p1;
    #pragma unroll
    for (int t = 0; t < 4; ++t) {
        (&p0.x)[t] = (unsigned)f2bf(a0[2*t] * (1.0f / DEG))
                   | ((unsigned)f2bf(a0[2*t+1] * (1.0f / DEG)) << 16);
        (&p1.x)[t] = (unsigned)f2bf(a1[2*t] * (1.0f / DEG))
                   | ((unsigned)f2bf(a1[2*t+1] * (1.0f / DEG)) << 16);
    }
    if (v0) *(uint4*)(hn + (size_t)n0 * F + sub * 8) = p0;
    if (v1) *(uint4*)(hn + (size_t)n1 * F + sub * 8) = p1;
}

// ---------------- streaming dense layer (unchanged from R6) ----------------
template<bool RELU, bool EMIT_BF16>
__global__ __launch_bounds__(256, 4)
void sage_dense(const float*  __restrict__ self_f32,  // [NN,F]
                const ushort* __restrict__ hn_bf16,   // [NN,F] bf16 means
                const float*  __restrict__ W,         // [KDIM,F]
                const float*  __restrict__ bias,      // [F]
                float*        __restrict__ out_f32,   // [NN,F]
                ushort*       __restrict__ out_bf16)  // [NN,F] or null
{
    __shared__ float buf[KDIM][STR];   // 33.3 KB, k-major

    const int tid   = threadIdx.x;
    const int lane  = tid & 63;
    const int wave  = __builtin_amdgcn_readfirstlane(tid >> 6);
    const int node0 = blockIdx.x * NPB;

    #pragma unroll 4
    for (int m = 0; m < NPB / 4; ++m) {
        const int n    = wave * (NPB / 4) + m;
        const int node = node0 + n;
        float v = 0.f, s = 0.f;
        if (node < NN) {
            v = self_f32[node * F + lane];
            s = bf2f(hn_bf16[node * F + lane]);
        }
        buf[lane][n]     = v;
        buf[F + lane][n] = s;
    }
    __syncthreads();

    const int j0 = wave * JPW;
    float acc[JPW];
    #pragma unroll
    for (int j = 0; j < JPW; ++j) acc[j] = bias[j0 + j];

    #pragma unroll 4
    for (int k = 0; k < KDIM; ++k) {
        const float v = buf[k][lane];
        const float* Wr = W + k * F + j0;
        #pragma unroll
        for (int j = 0; j < JPW; ++j)
            acc[j] = fmaf(v, Wr[j], acc[j]);
    }

    const int node = node0 + lane;
    if (node < NN) {
        if (RELU) {
            #pragma unroll
            for (int j = 0; j < JPW; ++j) acc[j] = fmaxf(acc[j], 0.f);
        }
        float4* op = (float4*)(out_f32 + node * F + j0);
        #pragma unroll
        for (int t = 0; t < 4; ++t)
            op[t] = make_float4(acc[4 * t], acc[4 * t + 1],
                                acc[4 * t + 2], acc[4 * t + 3]);
        if (EMIT_BF16) {
            uint4 q0, q1;
            #pragma unroll
            for (int t = 0; t < 8; ++t)
                (t < 4 ? (&q0.x)[t] : (&q1.x)[t - 4]) =
                    (unsigned)f2bf(acc[2 * t]) |
                    ((unsigned)f2bf(acc[2 * t + 1]) << 16);
            uint4* ob = (uint4*)(out_bf16 + node * F + j0);
            ob[0] = q0; ob[1] = q1;
        }
    }
}

// ---------------- fallback (round-3, all-fp32, fused) ----------------
template<bool RELU>
__global__ __launch_bounds__(256, 4)
void sage_layer_f32(const float* __restrict__ feat,
                    const float* __restrict__ W,
                    const float* __restrict__ bias,
                    const int*   __restrict__ src,
                    float*       __restrict__ out)
{
    __shared__ float buf[KDIM][STR];
    const int tid   = threadIdx.x;
    const int lane  = tid & 63;
    const int wave  = __builtin_amdgcn_readfirstlane(tid >> 6);
    const int node0 = blockIdx.x * NPB;

    #pragma unroll 2
    for (int m = 0; m < NPB / 4; ++m) {
        const int n    = wave * (NPB / 4) + m;
        const int node = node0 + n;
        if (node < NN) {
            buf[lane][n] = feat[node * F + lane];
            const int* sp = src + node * DEG;
            float s = 0.f;
            #pragma unroll
            for (int e = 0; e < DEG; ++e) s += feat[sp[e] * F + lane];
            buf[F + lane][n] = s * (1.0f / DEG);
        }
    }
    __syncthreads();

    const int j0 = wave * JPW;
    float acc[JPW];
    #pragma unroll
    for (int j = 0; j < JPW; ++j) acc[j] = bias[j0 + j];
    #pragma unroll 4
    for (int k = 0; k < KDIM; ++k) {
        const float v = buf[k][lane];
        const float* Wr = W + k * F + j0;
        #pragma unroll
        for (int j = 0; j < JPW; ++j) acc[j] = fmaf(v, Wr[j], acc[j]);
    }
    const int node = node0 + lane;
    if (node < NN) {
        float4* op = (float4*)(out + node * F + j0);
        #pragma unroll
        for (int t = 0; t < 4; ++t) {
            float4 r = make_float4(acc[4 * t], acc[4 * t + 1],
                                   acc[4 * t + 2], acc[4 * t + 3]);
            if (RELU) {
                r.x = fmaxf(r.x, 0.f); r.y = fmaxf(r.y, 0.f);
                r.z = fmaxf(r.z, 0.f); r.w = fmaxf(r.w, 0.f);
            }
            op[t] = r;
        }
    }
}

extern "C" void kernel_launch(void* const* d_in, const int* in_sizes, int n_in,
                              void* d_out, int out_size, void* d_ws, size_t ws_size,
                              hipStream_t stream) {
    const float* x   = (const float*)d_in[0];
    const float* W1  = (const float*)d_in[1];
    const float* b1  = (const float*)d_in[2];
    const float* W2  = (const float*)d_in[3];
    const float* b2  = (const float*)d_in[4];
    const int*   src = (const int*)d_in[5];

    float* out = (float*)d_out;
    const int dblocks = (NN + NPB - 1) / NPB;   // 1563

    const size_t hF32 = (size_t)NN * F * sizeof(float);   // 25.6 MB
    const size_t hBF  = (size_t)NN * F * sizeof(ushort);  // 12.8 MB

    if (ws_size >= hF32 + 2 * hBF) {
        // C = h_f32 (25.6MB), A = x_bf16 then h_bf16 (12.8MB), B = hn (12.8MB)
        float*  C = (float*)d_ws;
        ushort* A = (ushort*)((char*)d_ws + hF32);
        ushort* B = (ushort*)((char*)d_ws + hF32 + hBF);

        const int n4 = NN * F / 4;
        cvt_f32_bf16<<<(n4 + 255) / 256, 256, 0, stream>>>(x, A, n4);
        gather_mean_sorted<<<GBLK, 256, 0, stream>>>(A, src, B);      // hn1
        sage_dense<true,  true ><<<dblocks, 256, 0, stream>>>(
            x, B, W1, b1, C, A);                                      // h, h_bf16
        gather_mean_sorted<<<GBLK, 256, 0, stream>>>(A, src, B);      // hn2
        sage_dense<false, false><<<dblocks, 256, 0, stream>>>(
            C, B, W2, b2, out, nullptr);
    } else {
        float* h = (float*)d_ws;
        sage_layer_f32<true ><<<dblocks, 256, 0, stream>>>(x, W1, b1, src, h);
        sage_layer_f32<false><<<dblocks, 256, 0, stream>>>(h, W2, b2, src, out);
    }
}

// Round 8
// 208.240 us; speedup vs baseline: 1.5092x; 1.3806x over previous
//
#include <hip/hip_runtime.h>

// SimpleGraphSAGE on MI355X — round 8.
// dst = repeat(arange(N),16) -> node i's edges are src[16i..16i+16), deg==16.
//
// History: R1 85us/layer; R3 83; R4 72 fused bf16; R5 flat (not inst-bound);
// R6 split: standalone gather 70us == R4 fused total -> matmul rides free
// under gather latency; dense kernel costs ~51us (wasted). R7: register-
// sorted srcs cut gather 70->57us (moving-window L2 locality), FETCH at the
// sorted-model floor (~125MB).
// R8: FUSE R7's sorted gather into R4's fused layer kernel; self path bf16;
// layer1 emits only h_bf16. 3 dispatches total, no hn round-trip.

#define NN   100000
#define DEG  16
#define F    64
#define KDIM 128
#define NPB  64       // nodes per block (256 threads, 4 waves)
#define STR  65       // LDS row stride (2-way bank alias = free)
#define JPW  16       // output columns per wave
#define EDG  (NN * DEG)

__device__ __forceinline__ ushort f2bf(float f) {        // RNE
    unsigned u = __float_as_uint(f);
    return (ushort)((u + 0x7fffu + ((u >> 16) & 1u)) >> 16);
}
__device__ __forceinline__ float bf2f(ushort u) {
    return __uint_as_float(((unsigned)u) << 16);
}

__global__ __launch_bounds__(256)
void cvt_f32_bf16(const float* __restrict__ in, ushort* __restrict__ out, int n4)
{
    int i = blockIdx.x * 256 + threadIdx.x;
    if (i < n4) {
        float4 v = ((const float4*)in)[i];
        ushort4 o;
        o.x = f2bf(v.x); o.y = f2bf(v.y); o.z = f2bf(v.z); o.w = f2bf(v.w);
        ((ushort4*)out)[i] = o;
    }
}

// Batcher odd-even mergesort, 16 keys, fully unrolled -> stays in registers.
__device__ __forceinline__ void ce(unsigned& a, unsigned& b) {
    const unsigned lo = min(a, b), hi = max(a, b); a = lo; b = hi;
}
__device__ __forceinline__ void sort16(unsigned s[16]) {
    #pragma unroll
    for (int p = 1; p < 16; p <<= 1) {
        #pragma unroll
        for (int k = p; k >= 1; k >>= 1) {
            #pragma unroll
            for (int j = k & (p - 1); j + k < 16; j += 2 * k) {
                #pragma unroll
                for (int i = 0; i < k; ++i) {
                    if (i + j + k < 16)
                        if ((i + j) / (2 * p) == (i + j + k) / (2 * p))
                            ce(s[i + j], s[i + j + k]);
                }
            }
        }
    }
}

// ---------------- fused layer: sorted gather + SGPR-W matmul ----------------
// in_bf16:  [NN,F] bf16 (self AND gather table).
// Gather: 8-lane group handles 2 nodes; sub-lane s holds features 8s..8s+8.
// Each group sorts both nodes' 16 srcs in registers -> device-wide edges are
// processed in ascending-src order -> moving L2 window.
// Matmul: lane = node, wave owns 16 output columns; W rows wave-uniform ->
// SMEM pipe (proven R3/R4 structure).
template<bool RELU, bool EMIT_F32>
__global__ __launch_bounds__(256, 4)
void sage_fused(const ushort* __restrict__ in_bf16,   // [NN,F]
                const float*  __restrict__ W,         // [KDIM,F]
                const float*  __restrict__ bias,      // [F]
                const int*    __restrict__ src,       // [EDG]
                float*        __restrict__ out_f32,   // if EMIT_F32
                ushort*       __restrict__ out_bf16)  // if !EMIT_F32
{
    __shared__ float buf[KDIM][STR];   // k-major, 33.3 KB

    const int tid   = threadIdx.x;
    const int lane  = tid & 63;
    const int wave  = __builtin_amdgcn_readfirstlane(tid >> 6);
    const int node0 = blockIdx.x * NPB;

    // ---- Self staging: lane = feature, wave stages its 16 nodes ----
    #pragma unroll 4
    for (int m = 0; m < JPW; ++m) {
        const int n    = wave * JPW + m;
        const int node = node0 + n;
        float v = 0.f;
        if (node < NN) v = bf2f(in_bf16[node * F + lane]);   // 128B coalesced
        buf[lane][n] = v;
    }

    // ---- Sorted gather: group (8 lanes) handles nodes n0loc, n0loc+1 ----
    {
        const int sub   = lane & 7;
        const int grp   = lane >> 3;
        const int n0loc = wave * JPW + grp * 2;
        const int n1loc = n0loc + 1;
        const int n0    = node0 + n0loc;
        const int n1    = node0 + n1loc;
        const bool v0   = n0 < NN, v1 = n1 < NN;

        unsigned s0[DEG], s1[DEG];
        {
            const int4* p0 = (const int4*)(src + (size_t)n0 * DEG);
            const int4* p1 = (const int4*)(src + (size_t)n1 * DEG);
            #pragma unroll
            for (int q = 0; q < 4; ++q) {
                const int4 a = v0 ? p0[q] : make_int4(0, 0, 0, 0);
                const int4 b = v1 ? p1[q] : make_int4(0, 0, 0, 0);
                s0[4*q+0] = a.x; s0[4*q+1] = a.y;
                s0[4*q+2] = a.z; s0[4*q+3] = a.w;
                s1[4*q+0] = b.x; s1[4*q+1] = b.y;
                s1[4*q+2] = b.z; s1[4*q+3] = b.w;
            }
        }
        sort16(s0);
        sort16(s1);

        float a0[8], a1[8];
        #pragma unroll
        for (int f = 0; f < 8; ++f) { a0[f] = 0.f; a1[f] = 0.f; }

        #pragma unroll
        for (int e = 0; e < DEG; e += 2) {
            const uint4 r00 = *(const uint4*)(in_bf16 + (size_t)s0[e]   * F + sub * 8);
            const uint4 r01 = *(const uint4*)(in_bf16 + (size_t)s0[e+1] * F + sub * 8);
            const uint4 r10 = *(const uint4*)(in_bf16 + (size_t)s1[e]   * F + sub * 8);
            const uint4 r11 = *(const uint4*)(in_bf16 + (size_t)s1[e+1] * F + sub * 8);
            #pragma unroll
            for (int t = 0; t < 4; ++t) {
                const unsigned w00 = (&r00.x)[t], w01 = (&r01.x)[t];
                const unsigned w10 = (&r10.x)[t], w11 = (&r11.x)[t];
                a0[2*t]   += __uint_as_float(w00 << 16);
                a0[2*t+1] += __uint_as_float(w00 & 0xffff0000u);
                a0[2*t]   += __uint_as_float(w01 << 16);
                a0[2*t+1] += __uint_as_float(w01 & 0xffff0000u);
                a1[2*t]   += __uint_as_float(w10 << 16);
                a1[2*t+1] += __uint_as_float(w10 & 0xffff0000u);
                a1[2*t]   += __uint_as_float(w11 << 16);
                a1[2*t+1] += __uint_as_float(w11 & 0xffff0000u);
            }
        }

        // Mean -> k-major LDS (feature F+8*sub+f, node column n0loc/n1loc).
        #pragma unroll
        for (int f = 0; f < 8; ++f) {
            buf[F + 8 * sub + f][n0loc] = a0[f] * (1.0f / DEG);
            buf[F + 8 * sub + f][n1loc] = a1[f] * (1.0f / DEG);
        }
    }
    __syncthreads();

    // ---- Matmul: lane = node, wave owns j in [16w,16w+16) ----
    const int j0 = wave * JPW;
    float acc[JPW];
    #pragma unroll
    for (int j = 0; j < JPW; ++j) acc[j] = bias[j0 + j];   // s_load

    #pragma unroll 4
    for (int k = 0; k < KDIM; ++k) {
        const float v = buf[k][lane];            // ds_read_b32, 2-way = free
        const float* Wr = W + k * F + j0;        // wave-uniform -> s_load
        #pragma unroll
        for (int j = 0; j < JPW; ++j)
            acc[j] = fmaf(v, Wr[j], acc[j]);
    }

    const int node = node0 + lane;
    if (node < NN) {
        if (RELU) {
            #pragma unroll
            for (int j = 0; j < JPW; ++j) acc[j] = fmaxf(acc[j], 0.f);
        }
        if (EMIT_F32) {
            float4* op = (float4*)(out_f32 + node * F + j0);
            #pragma unroll
            for (int t = 0; t < 4; ++t)
                op[t] = make_float4(acc[4 * t], acc[4 * t + 1],
                                    acc[4 * t + 2], acc[4 * t + 3]);
        } else {
            uint4 q0, q1;
            #pragma unroll
            for (int t = 0; t < 8; ++t)
                (t < 4 ? (&q0.x)[t] : (&q1.x)[t - 4]) =
                    (unsigned)f2bf(acc[2 * t]) |
                    ((unsigned)f2bf(acc[2 * t + 1]) << 16);
            uint4* ob = (uint4*)(out_bf16 + node * F + j0);  // 32B
            ob[0] = q0; ob[1] = q1;
        }
    }
}

// ---------------- fallback (round-3, all-fp32, fused) ----------------
template<bool RELU>
__global__ __launch_bounds__(256, 4)
void sage_layer_f32(const float* __restrict__ feat,
                    const float* __restrict__ W,
                    const float* __restrict__ bias,
                    const int*   __restrict__ src,
                    float*       __restrict__ out)
{
    __shared__ float buf[KDIM][STR];
    const int tid   = threadIdx.x;
    const int lane  = tid & 63;
    const int wave  = __builtin_amdgcn_readfirstlane(tid >> 6);
    const int node0 = blockIdx.x * NPB;

    #pragma unroll 2
    for (int m = 0; m < NPB / 4; ++m) {
        const int n    = wave * (NPB / 4) + m;
        const int node = node0 + n;
        if (node < NN) {
            buf[lane][n] = feat[node * F + lane];
            const int* sp = src + node * DEG;
            float s = 0.f;
            #pragma unroll
            for (int e = 0; e < DEG; ++e) s += feat[sp[e] * F + lane];
            buf[F + lane][n] = s * (1.0f / DEG);
        }
    }
    __syncthreads();

    const int j0 = wave * JPW;
    float acc[JPW];
    #pragma unroll
    for (int j = 0; j < JPW; ++j) acc[j] = bias[j0 + j];
    #pragma unroll 4
    for (int k = 0; k < KDIM; ++k) {
        const float v = buf[k][lane];
        const float* Wr = W + k * F + j0;
        #pragma unroll
        for (int j = 0; j < JPW; ++j) acc[j] = fmaf(v, Wr[j], acc[j]);
    }
    const int node = node0 + lane;
    if (node < NN) {
        float4* op = (float4*)(out + node * F + j0);
        #pragma unroll
        for (int t = 0; t < 4; ++t) {
            float4 r = make_float4(acc[4 * t], acc[4 * t + 1],
                                   acc[4 * t + 2], acc[4 * t + 3]);
            if (RELU) {
                r.x = fmaxf(r.x, 0.f); r.y = fmaxf(r.y, 0.f);
                r.z = fmaxf(r.z, 0.f); r.w = fmaxf(r.w, 0.f);
            }
            op[t] = r;
        }
    }
}

extern "C" void kernel_launch(void* const* d_in, const int* in_sizes, int n_in,
                              void* d_out, int out_size, void* d_ws, size_t ws_size,
                              hipStream_t stream) {
    const float* x   = (const float*)d_in[0];
    const float* W1  = (const float*)d_in[1];
    const float* b1  = (const float*)d_in[2];
    const float* W2  = (const float*)d_in[3];
    const float* b2  = (const float*)d_in[4];
    const int*   src = (const int*)d_in[5];

    float* out = (float*)d_out;
    const int blocks = (NN + NPB - 1) / NPB;   // 1563

    const size_t hBF = (size_t)NN * F * sizeof(ushort);  // 12.8 MB

    if (ws_size >= 2 * hBF) {
        ushort* A = (ushort*)d_ws;                 // x_bf16
        ushort* B = (ushort*)((char*)d_ws + hBF);  // h_bf16

        const int n4 = NN * F / 4;
        cvt_f32_bf16<<<(n4 + 255) / 256, 256, 0, stream>>>(x, A, n4);
        sage_fused<true,  false><<<blocks, 256, 0, stream>>>(
            A, W1, b1, src, nullptr, B);           // layer1 -> h_bf16
        sage_fused<false, true ><<<blocks, 256, 0, stream>>>(
            B, W2, b2, src, out, nullptr);         // layer2 -> fp32 out
    } else {
        float* h = (float*)d_ws;
        sage_layer_f32<true ><<<blocks, 256, 0, stream>>>(x, W1, b1, src, h);
        sage_layer_f32<false><<<blocks, 256, 0, stream>>>(h, W2, b2, src, out);
    }
}